// Round 1
// baseline (309.312 us; speedup 1.0000x reference)
//
#include <hip/hip_runtime.h>

#define PI_F 3.14159265358979323846f

// ---------- complex 2x2 helpers ----------
struct C2 { float r, i; };
struct M2 { C2 m[2][2]; };

__device__ __forceinline__ C2 cmul(C2 a, C2 b){ return C2{a.r*b.r - a.i*b.i, a.r*b.i + a.i*b.r}; }
__device__ __forceinline__ C2 cadd(C2 a, C2 b){ return C2{a.r+b.r, a.i+b.i}; }

__device__ __forceinline__ M2 mmul(M2 A, M2 B){
  M2 R;
  #pragma unroll
  for (int r=0;r<2;++r)
    #pragma unroll
    for (int c=0;c<2;++c)
      R.m[r][c] = cadd(cmul(A.m[r][0],B.m[0][c]), cmul(A.m[r][1],B.m[1][c]));
  return R;
}
__device__ __forceinline__ M2 m_rx(float t){ float s,c; sincosf(0.5f*t,&s,&c);
  M2 U; U.m[0][0]=C2{c,0}; U.m[0][1]=C2{0,-s}; U.m[1][0]=C2{0,-s}; U.m[1][1]=C2{c,0}; return U; }
__device__ __forceinline__ M2 m_ry(float t){ float s,c; sincosf(0.5f*t,&s,&c);
  M2 U; U.m[0][0]=C2{c,0}; U.m[0][1]=C2{-s,0}; U.m[1][0]=C2{s,0}; U.m[1][1]=C2{c,0}; return U; }
__device__ __forceinline__ M2 m_rz(float t){ float s,c; sincosf(0.5f*t,&s,&c);
  M2 U; U.m[0][0]=C2{c,-s}; U.m[0][1]=C2{0,0}; U.m[1][0]=C2{0,0}; U.m[1][1]=C2{c,s}; return U; }
__device__ __forceinline__ M2 fuse_zy(float tz, float ty){ return mmul(m_rz(tz), m_ry(ty)); }
__device__ __forceinline__ M2 fuse_zyx(float tz, float ty, float tx){ return mmul(m_rz(tz), mmul(m_ry(ty), m_rx(tx))); }

// Qubit->bit mapping for flat amp index f = lane*8 + r (f bit (8-q) = qubit q):
//  q=0..5 -> lane bit (5-q)  (shfl mask 1<<(5-q))
//  q=6,7,8 -> r bit (8-q)    (stride 1<<(8-q))
template<int Q>
__device__ __forceinline__ int qbit(int lane, int r){
  if constexpr (Q <= 5) return (lane >> (5-Q)) & 1;
  else                  return (r    >> (8-Q)) & 1;
}

// single-qubit gate on a register qubit (stride = 1,2,4 for q=8,7,6)
template<int STRIDE>
__device__ __forceinline__ void applyReg(M2 U, float (&sr)[8], float (&si)[8]){
  #pragma unroll
  for (int r0=0;r0<8;++r0){
    if (r0 & STRIDE) continue;
    const int r1 = r0 | STRIDE;
    C2 a0{sr[r0], si[r0]}, a1{sr[r1], si[r1]};
    C2 n0 = cadd(cmul(U.m[0][0],a0), cmul(U.m[0][1],a1));
    C2 n1 = cadd(cmul(U.m[1][0],a0), cmul(U.m[1][1],a1));
    sr[r0]=n0.r; si[r0]=n0.i; sr[r1]=n1.r; si[r1]=n1.i;
  }
}

// single-qubit gate on a lane qubit (MASK = 1<<(5-q))
template<int MASK>
__device__ __forceinline__ void applyLane(M2 U, float (&sr)[8], float (&si)[8], int lane){
  const bool b = (lane & MASK) != 0;
  const C2 cs = b ? U.m[1][1] : U.m[0][0];   // coeff on own amplitude
  const C2 cp = b ? U.m[1][0] : U.m[0][1];   // coeff on partner amplitude
  #pragma unroll
  for (int j=0;j<8;++j){
    float pr  = __shfl_xor(sr[j], MASK);
    float pim = __shfl_xor(si[j], MASK);
    float nr = cs.r*sr[j] - cs.i*si[j] + cp.r*pr  - cp.i*pim;
    float ni = cs.r*si[j] + cs.i*sr[j] + cp.r*pim + cp.i*pr;
    sr[j]=nr; si[j]=ni;
  }
}

// controlled-U: control on a lane bit (CMASK), target a register qubit (STRIDE)
template<int STRIDE, int CMASK>
__device__ __forceinline__ void applyCtrlReg(M2 U, float (&sr)[8], float (&si)[8], int lane){
  const bool c = (lane & CMASK) != 0;
  M2 E;
  E.m[0][0] = c ? U.m[0][0] : C2{1.f,0.f};
  E.m[0][1] = c ? U.m[0][1] : C2{0.f,0.f};
  E.m[1][0] = c ? U.m[1][0] : C2{0.f,0.f};
  E.m[1][1] = c ? U.m[1][1] : C2{1.f,0.f};
  applyReg<STRIDE>(E, sr, si);
}

template<int QA, int QB>
__device__ __forceinline__ void applyCZ(float (&sr)[8], float (&si)[8], int lane){
  #pragma unroll
  for (int r=0;r<8;++r){
    if (qbit<QA>(lane,r) & qbit<QB>(lane,r)){ sr[r]=-sr[r]; si[r]=-si[r]; }
  }
}

// ---------- MLP kernel (x -> lrelu(x@W1+b1) -> @W2+b2 -> PI*tanh) ----------
template<int IN>
__global__ void mlp_kernel(const float* __restrict__ x,
                           const float* __restrict__ W1, const float* __restrict__ b1,
                           const float* __restrict__ W2, const float* __restrict__ b2,
                           float* __restrict__ out, int M){
  int row = blockIdx.x*blockDim.x + threadIdx.x;
  if (row >= M) return;
  float xi[IN];
  #pragma unroll
  for (int i=0;i<IN;++i) xi[i] = x[row*IN+i];
  float a0 = b2[0], a1 = b2[1];
  #pragma unroll 4
  for (int j=0;j<128;++j){
    float h = b1[j];
    #pragma unroll
    for (int i=0;i<IN;++i) h = fmaf(xi[i], W1[i*128+j], h);
    h = h > 0.f ? h : 0.2f*h;
    a0 = fmaf(h, W2[j*2+0], a0);
    a1 = fmaf(h, W2[j*2+1], a1);
  }
  out[row*2+0] = PI_F * tanhf(a0);
  out[row*2+1] = PI_F * tanhf(a1);
}

// ---------- PQC + update MLP + graph accumulation (one wave per node) ----------
__global__ void pqc_kernel(const float* __restrict__ node_f, const float* __restrict__ edge_f,
                           const int* __restrict__ gn, const int* __restrict__ ge,
                           const float* __restrict__ theta,
                           const float* __restrict__ uW1, const float* __restrict__ ub1,
                           const float* __restrict__ uW2, const float* __restrict__ ub2,
                           const int* __restrict__ batch,
                           float* __restrict__ gacc, float* __restrict__ gcnt,
                           int N){
  const int lane = threadIdx.x & 63;
  const int n = blockIdx.x*4 + (threadIdx.x >> 6);
  if (n >= N) return;

  // gather data[18]
  float d[18];
  #pragma unroll
  for (int j=0;j<3;++j){
    int e = ge[n*3+j];
    bool ok = e >= 0; int idx = ok ? e : 0;
    d[2*j+0] = ok ? edge_f[idx*2+0] : 0.f;
    d[2*j+1] = ok ? edge_f[idx*2+1] : 0.f;
  }
  #pragma unroll
  for (int j=0;j<4;++j){
    int v = gn[n*4+j];
    bool ok = v >= 0; int idx = ok ? v : 0;
    d[6+2*j+0] = ok ? node_f[idx*2+0] : 0.f;
    d[6+2*j+1] = ok ? node_f[idx*2+1] : 0.f;
  }
  d[14]=d[8]; d[15]=d[0]; d[16]=d[9]; d[17]=d[1];

  // state: 8 complex amps / lane
  float sr[8], si[8];
  #pragma unroll
  for (int j=0;j<8;++j){ sr[j]=0.f; si[j]=0.f; }
  if (lane==0) sr[0]=1.f;

  // layer 1+2: fused ry->rz per qubit
  applyLane<32>(fuse_zy(d[1], d[0]), sr, si, lane);   // q0
  applyLane<16>(fuse_zy(d[3], d[2]), sr, si, lane);   // q1
  applyLane< 8>(fuse_zy(d[5], d[4]), sr, si, lane);   // q2
  applyLane< 4>(fuse_zy(d[7], d[6]), sr, si, lane);   // q3
  applyLane< 2>(fuse_zy(d[9], d[8]), sr, si, lane);   // q4
  applyLane< 1>(fuse_zy(d[11],d[10]), sr, si, lane);  // q5
  applyReg < 4>(fuse_zy(d[13],d[12]), sr, si);        // q6

  // controlled gates
  applyCtrlReg<2, 2>(m_rx(d[14]), sr, si, lane);  // crx c=4 t=7
  applyCtrlReg<2,32>(m_ry(d[15]), sr, si, lane);  // cry c=0 t=7
  applyCtrlReg<1, 2>(m_rz(d[16]), sr, si, lane);  // crz c=4 t=8
  applyCtrlReg<1,32>(m_ry(d[17]), sr, si, lane);  // cry c=0 t=8

  // theta blocks (rx->ry->rz fused per qubit)
  const float* th = theta;
  // block 0: qs = (0,4,7)
  applyLane<32>(fuse_zyx(th[2], th[1], th[0]), sr, si, lane);
  applyLane< 2>(fuse_zyx(th[5], th[4], th[3]), sr, si, lane);
  applyReg < 2>(fuse_zyx(th[8], th[7], th[6]), sr, si);
  applyCZ<0,4>(sr, si, lane); applyCZ<4,7>(sr, si, lane); applyCZ<7,0>(sr, si, lane);
  // block 1: qs = (7,4,8)
  applyReg < 2>(fuse_zyx(th[11],th[10],th[ 9]), sr, si);
  applyLane< 2>(fuse_zyx(th[14],th[13],th[12]), sr, si, lane);
  applyReg < 1>(fuse_zyx(th[17],th[16],th[15]), sr, si);
  applyCZ<7,4>(sr, si, lane); applyCZ<4,8>(sr, si, lane); applyCZ<8,7>(sr, si, lane);
  // block 2: qs = (3,7,8)
  applyLane< 4>(fuse_zyx(th[20],th[19],th[18]), sr, si, lane);
  applyReg < 2>(fuse_zyx(th[23],th[22],th[21]), sr, si);
  applyReg < 1>(fuse_zyx(th[26],th[25],th[24]), sr, si);
  applyCZ<3,7>(sr, si, lane); applyCZ<7,8>(sr, si, lane); applyCZ<8,3>(sr, si, lane);

  // <psi| X_3 |psi>  (qubit 3 = lane bit 2, shfl mask 4)
  float acc = 0.f;
  #pragma unroll
  for (int j=0;j<8;++j){
    float pr  = __shfl_xor(sr[j], 4);
    float pim = __shfl_xor(si[j], 4);
    acc += sr[j]*pr + si[j]*pim;
  }
  #pragma unroll
  for (int m=32; m; m>>=1) acc += __shfl_xor(acc, m);
  // all lanes now hold exp

  // update MLP: [nf0, nf1, exp] -> 128 (lrelu) -> 2
  const int g0 = gn[n*4+0];
  const float inp0 = node_f[g0*2+0];
  const float inp1 = node_f[g0*2+1];
  float a0 = 0.f, a1 = 0.f;
  #pragma unroll
  for (int t=0;t<2;++t){
    int j = lane + 64*t;
    float h = ub1[j];
    h = fmaf(inp0, uW1[0*128+j], h);
    h = fmaf(inp1, uW1[1*128+j], h);
    h = fmaf(acc , uW1[2*128+j], h);
    h = h > 0.f ? h : 0.2f*h;
    a0 = fmaf(h, uW2[j*2+0], a0);
    a1 = fmaf(h, uW2[j*2+1], a1);
  }
  #pragma unroll
  for (int m=32; m; m>>=1){ a0 += __shfl_xor(a0, m); a1 += __shfl_xor(a1, m); }

  if (lane==0){
    float upd0 = a0 + ub2[0];
    float upd1 = a1 + ub2[1];
    // original node_f[n] contributes to graph batch[n]; upd contributes to graph batch[gn0]
    float nf0 = node_f[n*2+0], nf1 = node_f[n*2+1];
    int bn  = batch[n];
    int bg0 = batch[g0];
    atomicAdd(&gacc[bn*2+0], nf0);
    atomicAdd(&gacc[bn*2+1], nf1);
    atomicAdd(&gacc[bg0*2+0], upd0);
    atomicAdd(&gacc[bg0*2+1], upd1);
    atomicAdd(&gcnt[bn], 1.f);
  }
}

// ---------- head MLP ----------
__global__ void head_kernel(const float* __restrict__ gacc, const float* __restrict__ gcnt,
                            const float* __restrict__ hW1, const float* __restrict__ hb1,
                            const float* __restrict__ hW2, const float* __restrict__ hb2,
                            float* __restrict__ out, int G){
  int g = threadIdx.x;
  if (g >= G) return;
  float inv = 1.f / gcnt[g];
  float e0 = gacc[g*2+0]*inv, e1 = gacc[g*2+1]*inv;
  float h0 = hb1[0] + e0*hW1[0*2+0] + e1*hW1[1*2+0];
  float h1 = hb1[1] + e0*hW1[0*2+1] + e1*hW1[1*2+1];
  h0 = h0 > 0.f ? h0 : 0.2f*h0;
  h1 = h1 > 0.f ? h1 : 0.2f*h1;
  out[g*2+0] = hb2[0] + h0*hW2[0*2+0] + h1*hW2[1*2+0];
  out[g*2+1] = hb2[1] + h0*hW2[0*2+1] + h1*hW2[1*2+1];
}

extern "C" void kernel_launch(void* const* d_in, const int* in_sizes, int n_in,
                              void* d_out, int out_size, void* d_ws, size_t ws_size,
                              hipStream_t stream) {
  const float* node_feat = (const float*)d_in[0];
  const float* edge_attr = (const float*)d_in[1];
  const float* nW1 = (const float*)d_in[2];
  const float* nb1 = (const float*)d_in[3];
  const float* nW2 = (const float*)d_in[4];
  const float* nb2 = (const float*)d_in[5];
  const float* eW1 = (const float*)d_in[6];
  const float* eb1 = (const float*)d_in[7];
  const float* eW2 = (const float*)d_in[8];
  const float* eb2 = (const float*)d_in[9];
  const float* theta = (const float*)d_in[10];
  const float* uW1 = (const float*)d_in[11];
  const float* ub1 = (const float*)d_in[12];
  const float* uW2 = (const float*)d_in[13];
  const float* ub2 = (const float*)d_in[14];
  const float* hW1 = (const float*)d_in[15];
  const float* hb1 = (const float*)d_in[16];
  const float* hW2 = (const float*)d_in[17];
  const float* hb2 = (const float*)d_in[18];
  const int* gn    = (const int*)d_in[19];
  const int* ge    = (const int*)d_in[20];
  const int* batch = (const int*)d_in[21];

  const int N = in_sizes[0] / 16;
  const int E = in_sizes[1] / 8;
  const int G = out_size / 2;

  float* node_f = (float*)d_ws;        // N*2
  float* edge_f = node_f + (size_t)N*2; // E*2
  float* gacc   = edge_f + (size_t)E*2; // G*2
  float* gcnt   = gacc + (size_t)G*2;   // G

  mlp_kernel<16><<<(N+255)/256, 256, 0, stream>>>(node_feat, nW1, nb1, nW2, nb2, node_f, N);
  mlp_kernel< 8><<<(E+255)/256, 256, 0, stream>>>(edge_attr, eW1, eb1, eW2, eb2, edge_f, E);
  hipMemsetAsync(gacc, 0, 3*G*sizeof(float), stream);
  pqc_kernel<<<(N+3)/4, 256, 0, stream>>>(node_f, edge_f, gn, ge, theta,
                                          uW1, ub1, uW2, ub2, batch, gacc, gcnt, N);
  head_kernel<<<1, 64, 0, stream>>>(gacc, gcnt, hW1, hb1, hW2, hb2, (float*)d_out, G);
}